// Round 1
// baseline (2076.898 us; speedup 1.0000x reference)
//
#include <hip/hip_runtime.h>
#include <math.h>

#define N_NODES 50000
#define N_EDGES 800000
#define EP (N_EDGES + N_NODES)   /* 850000 edges incl. self-loops */
#define IN_CH 128
#define HID 64
#define HEADS 4
#define HC (HID * HEADS)         /* 256 */
#define OUT_CH 128
#define NEG_SLOPE 0.2f

// ---- monotone float<->uint mapping for atomicMax on floats ----
__device__ __forceinline__ unsigned f2o(float f) {
    unsigned u = __float_as_uint(f);
    return (u & 0x80000000u) ? ~u : (u | 0x80000000u);
}
__device__ __forceinline__ float o2f(unsigned u) {
    return (u & 0x80000000u) ? __uint_as_float(u ^ 0x80000000u)
                             : __uint_as_float(~u);
}

// ---- layer-1 GEMM: H1 = x@W1, XL1 = x@lin1_w, plus attention dots ----
// one block (256 thr) per node row; x row staged in LDS
__global__ void gemm1_kernel(const float* __restrict__ x,
                             const float* __restrict__ W1,
                             const float* __restrict__ L1,
                             const float* __restrict__ att_src,
                             const float* __restrict__ att_dst,
                             float* __restrict__ H1, float* __restrict__ XL1,
                             float* __restrict__ AS, float* __restrict__ AD) {
    __shared__ float xs[IN_CH];
    int n = blockIdx.x;
    int j = threadIdx.x;                     // 0..255 output column
    if (j < IN_CH) xs[j] = x[n * IN_CH + j];
    __syncthreads();
    float a1 = 0.f, a2 = 0.f;
#pragma unroll 8
    for (int k = 0; k < IN_CH; ++k) {
        float xv = xs[k];
        a1 += xv * W1[k * HC + j];
        a2 += xv * L1[k * HC + j];
    }
    H1[n * HC + j] = a1;
    XL1[n * HC + j] = a2;
    // attention dots: head h = j>>6, channel c = j&63; wave h covers head h
    int lane = j & 63, h = j >> 6;
    float vs = a1 * att_src[h * HID + lane];
    float vd = a1 * att_dst[h * HID + lane];
#pragma unroll
    for (int off = 32; off; off >>= 1) {
        vs += __shfl_down(vs, off, 64);
        vd += __shfl_down(vd, off, 64);
    }
    if (lane == 0) { AS[n * HEADS + h] = vs; AD[n * HEADS + h] = vd; }
}

// ---- layer-2 GEMM: H2 = h@W2 (thr 0..127), XL2 = h@lin2_w (thr 128..255) ----
__global__ void gemm2_kernel(const float* __restrict__ h,
                             const float* __restrict__ W2,
                             const float* __restrict__ L2,
                             const float* __restrict__ att_src2,
                             const float* __restrict__ att_dst2,
                             float* __restrict__ H2, float* __restrict__ XL2,
                             float* __restrict__ AS, float* __restrict__ AD) {
    __shared__ float hs[HC];
    __shared__ float red[8];
    int n = blockIdx.x, j = threadIdx.x;     // 256 threads
    hs[j] = h[n * HC + j];
    __syncthreads();
    bool isH2 = j < OUT_CH;
    const float* Wp = isH2 ? W2 : L2;
    int col = isH2 ? j : j - OUT_CH;
    float acc = 0.f;
#pragma unroll 8
    for (int k = 0; k < HC; ++k) acc += hs[k] * Wp[k * OUT_CH + col];
    if (isH2) H2[n * OUT_CH + col] = acc;
    else      XL2[n * OUT_CH + col] = acc;
    float vs = isH2 ? acc * att_src2[col] : 0.f;
    float vd = isH2 ? acc * att_dst2[col] : 0.f;
#pragma unroll
    for (int off = 32; off; off >>= 1) {
        vs += __shfl_down(vs, off, 64);
        vd += __shfl_down(vd, off, 64);
    }
    int lane = j & 63, w = j >> 6;
    if (lane == 0) { red[w] = vs; red[4 + w] = vd; }
    __syncthreads();
    if (j == 0) AS[n] = red[0] + red[1];
    if (j == 1) AD[n] = red[4] + red[5];
}

// ---- edge pass 1: leaky_relu logit, store, atomic segment max ----
template <int H>
__global__ void edge_max_kernel(const int* __restrict__ ei,
                                const float* __restrict__ AS,
                                const float* __restrict__ AD,
                                float* __restrict__ EL,
                                unsigned* __restrict__ M) {
    long idx = (long)blockIdx.x * blockDim.x + threadIdx.x;
    if (idx >= (long)EP * H) return;
    int e = (int)(idx / H), hh = (int)(idx % H);
    int s, d;
    if (e < N_EDGES) { s = ei[e]; d = ei[N_EDGES + e]; }
    else             { s = d = e - N_EDGES; }
    float v = AS[s * H + hh] + AD[d * H + hh];
    v = v > 0.f ? v : NEG_SLOPE * v;
    EL[idx] = v;
    atomicMax(&M[d * H + hh], f2o(v));
}

// ---- edge pass 2: exp(logit - max), store, atomic segment sum ----
template <int H>
__global__ void edge_sum_kernel(const int* __restrict__ ei,
                                const unsigned* __restrict__ M,
                                float* __restrict__ EL,
                                float* __restrict__ S) {
    long idx = (long)blockIdx.x * blockDim.x + threadIdx.x;
    if (idx >= (long)EP * H) return;
    int e = (int)(idx / H), hh = (int)(idx % H);
    int d = (e < N_EDGES) ? ei[N_EDGES + e] : e - N_EDGES;
    float m = o2f(M[d * H + hh]);
    float el = expf(EL[idx] - m);
    EL[idx] = el;
    atomicAdd(&S[d * H + hh], el);
}

// ---- edge pass 3 (layer 1): GAT[d] += alpha * H1[s], block per edge ----
__global__ void edge_agg1_kernel(const int* __restrict__ ei,
                                 const float* __restrict__ EL,
                                 const float* __restrict__ S,
                                 const float* __restrict__ H1,
                                 float* __restrict__ GAT) {
    int e = blockIdx.x, j = threadIdx.x;     // 256 threads = all channels
    int s, d;
    if (e < N_EDGES) { s = ei[e]; d = ei[N_EDGES + e]; }
    else             { s = d = e - N_EDGES; }
    int hh = j >> 6;
    float alpha = EL[e * HEADS + hh] / (S[d * HEADS + hh] + 1e-16f);
    atomicAdd(&GAT[d * HC + j], alpha * H1[s * HC + j]);
}

// ---- edge pass 3 (layer 2): 1 head, 128 channels ----
__global__ void edge_agg2_kernel(const int* __restrict__ ei,
                                 const float* __restrict__ EL,
                                 const float* __restrict__ S,
                                 const float* __restrict__ H2,
                                 float* __restrict__ GAT) {
    int e = blockIdx.x, j = threadIdx.x;     // 128 threads
    int s, d;
    if (e < N_EDGES) { s = ei[e]; d = ei[N_EDGES + e]; }
    else             { s = d = e - N_EDGES; }
    float alpha = EL[e] / (S[d] + 1e-16f);
    atomicAdd(&GAT[d * OUT_CH + j], alpha * H2[s * OUT_CH + j]);
}

// ---- h = ELU(GAT1 + b1 + XL1 + lin1_b), in-place into GAT1 buffer ----
__global__ void combine1_kernel(float* __restrict__ HB,
                                const float* __restrict__ XL1,
                                const float* __restrict__ b1,
                                const float* __restrict__ l1b) {
    long i = (long)blockIdx.x * blockDim.x + threadIdx.x;
    if (i >= (long)N_NODES * HC) return;
    int j = (int)(i & (HC - 1));
    float v = HB[i] + XL1[i] + b1[j] + l1b[j];
    HB[i] = v > 0.f ? v : expm1f(v);
}

// ---- out = GAT2 + b2 + XL2 + lin2_b ----
__global__ void final_kernel(const float* __restrict__ GAT2,
                             const float* __restrict__ XL2,
                             const float* __restrict__ b2,
                             const float* __restrict__ l2b,
                             float* __restrict__ out) {
    long i = (long)blockIdx.x * blockDim.x + threadIdx.x;
    if (i >= (long)N_NODES * OUT_CH) return;
    int j = (int)(i & (OUT_CH - 1));
    out[i] = GAT2[i] + XL2[i] + b2[j] + l2b[j];
}

extern "C" void kernel_launch(void* const* d_in, const int* in_sizes, int n_in,
                              void* d_out, int out_size, void* d_ws, size_t ws_size,
                              hipStream_t stream) {
    const float* x    = (const float*)d_in[0];
    const int*   ei   = (const int*)d_in[1];
    const float* W1   = (const float*)d_in[2];
    const float* as1  = (const float*)d_in[3];
    const float* ad1  = (const float*)d_in[4];
    const float* b1   = (const float*)d_in[5];
    const float* l1w  = (const float*)d_in[6];
    const float* l1b  = (const float*)d_in[7];
    const float* W2   = (const float*)d_in[8];
    const float* as2  = (const float*)d_in[9];
    const float* ad2  = (const float*)d_in[10];
    const float* b2   = (const float*)d_in[11];
    const float* l2w  = (const float*)d_in[12];
    const float* l2b  = (const float*)d_in[13];
    float* out = (float*)d_out;

    // workspace layout (floats)
    float* ws   = (float*)d_ws;
    float* H1   = ws;                         // N*256
    float* XL1  = H1 + (size_t)N_NODES * HC;  // N*256
    float* HB   = XL1 + (size_t)N_NODES * HC; // N*256: GAT1 accum -> h (in place)
    float* EL   = HB + (size_t)N_NODES * HC;  // EP*4
    float* AS1  = EL + (size_t)EP * HEADS;    // N*4
    float* AD1  = AS1 + (size_t)N_NODES * HEADS;
    unsigned* M1 = (unsigned*)(AD1 + (size_t)N_NODES * HEADS); // N*4
    float* S1   = (float*)(M1 + (size_t)N_NODES * HEADS);      // N*4
    // layer-2 reuse
    float* H2   = H1;                          // N*128
    float* XL2  = H1 + (size_t)N_NODES * OUT_CH; // N*128 (2nd half of H1 region)
    float* GAT2 = XL1;                         // N*128 (reuse XL1 region)
    float* EL2  = EL;                          // EP
    float* AS2  = AS1; float* AD2 = AD1;
    unsigned* M2 = M1; float* S2 = S1;

    // ---- layer 1 ----
    hipMemsetAsync(HB, 0, (size_t)N_NODES * HC * 4, stream);
    hipMemsetAsync(M1, 0, (size_t)N_NODES * HEADS * 4, stream);
    hipMemsetAsync(S1, 0, (size_t)N_NODES * HEADS * 4, stream);

    gemm1_kernel<<<N_NODES, 256, 0, stream>>>(x, W1, l1w, as1, ad1, H1, XL1, AS1, AD1);

    int nEH1 = (EP * HEADS + 255) / 256;
    edge_max_kernel<HEADS><<<nEH1, 256, 0, stream>>>(ei, AS1, AD1, EL, M1);
    edge_sum_kernel<HEADS><<<nEH1, 256, 0, stream>>>(ei, M1, EL, S1);
    edge_agg1_kernel<<<EP, 256, 0, stream>>>(ei, EL, S1, H1, HB);

    combine1_kernel<<<(N_NODES * HC + 255) / 256, 256, 0, stream>>>(HB, XL1, b1, l1b);

    // ---- layer 2 ----
    hipMemsetAsync(GAT2, 0, (size_t)N_NODES * OUT_CH * 4, stream);
    hipMemsetAsync(M2, 0, (size_t)N_NODES * 4, stream);
    hipMemsetAsync(S2, 0, (size_t)N_NODES * 4, stream);

    gemm2_kernel<<<N_NODES, 256, 0, stream>>>(HB, W2, l2w, as2, ad2, H2, XL2, AS2, AD2);

    int nEH2 = (EP + 255) / 256;
    edge_max_kernel<1><<<nEH2, 256, 0, stream>>>(ei, AS2, AD2, EL2, M2);
    edge_sum_kernel<1><<<nEH2, 256, 0, stream>>>(ei, M2, EL2, S2);
    edge_agg2_kernel<<<EP, 128, 0, stream>>>(ei, EL2, S2, H2, GAT2);

    final_kernel<<<(N_NODES * OUT_CH + 255) / 256, 256, 0, stream>>>(GAT2, XL2, b2, l2b, out);
}

// Round 2
// 937.023 us; speedup vs baseline: 2.2165x; 2.2165x over previous
//
#include <hip/hip_runtime.h>
#include <math.h>

#define N_NODES 50000
#define N_EDGES 800000
#define EP (N_EDGES + N_NODES)   /* 850000 edges incl. self-loops */
#define IN_CH 128
#define HID 64
#define HEADS 4
#define HC (HID * HEADS)         /* 256 */
#define OUT_CH 128
#define NEG_SLOPE 0.2f
#define NB 8                      /* nodes per GEMM block */

// ---- monotone float<->uint mapping for atomicMax on floats ----
__device__ __forceinline__ unsigned f2o(float f) {
    unsigned u = __float_as_uint(f);
    return (u & 0x80000000u) ? ~u : (u | 0x80000000u);
}
__device__ __forceinline__ float o2f(unsigned u) {
    return (u & 0x80000000u) ? __uint_as_float(u ^ 0x80000000u)
                             : __uint_as_float(~u);
}

// ================= CSR build (topology only, shared by both layers) ========
__global__ void hist_kernel(const int* __restrict__ ei, int* __restrict__ cnt) {
    int e = blockIdx.x * 256 + threadIdx.x;
    if (e >= EP) return;
    int d = (e < N_EDGES) ? ei[N_EDGES + e] : e - N_EDGES;
    atomicAdd(&cnt[d], 1);
}

// single-block chunked Hillis-Steele exclusive scan; writes row[] and pos[]
__global__ void scan_kernel(const int* __restrict__ cnt,
                            int* __restrict__ row, int* __restrict__ pos) {
    __shared__ int buf[1024];
    __shared__ int carry;
    if (threadIdx.x == 0) carry = 0;
    __syncthreads();
    for (int base = 0; base < N_NODES; base += 1024) {
        int i = base + threadIdx.x;
        int v = (i < N_NODES) ? cnt[i] : 0;
        buf[threadIdx.x] = v;
        __syncthreads();
        for (int off = 1; off < 1024; off <<= 1) {
            int t = (threadIdx.x >= off) ? buf[threadIdx.x - off] : 0;
            __syncthreads();
            buf[threadIdx.x] += t;
            __syncthreads();
        }
        if (i < N_NODES) {
            int excl = carry + buf[threadIdx.x] - v;
            row[i] = excl; pos[i] = excl;
        }
        int total = buf[1023];
        __syncthreads();
        if (threadIdx.x == 0) carry += total;
        __syncthreads();
    }
    if (threadIdx.x == 0) row[N_NODES] = carry;
}

__global__ void scatter_kernel(const int* __restrict__ ei,
                               int* __restrict__ pos, int2* __restrict__ adj) {
    int e = blockIdx.x * 256 + threadIdx.x;
    if (e >= EP) return;
    int s, d;
    if (e < N_EDGES) { s = ei[e]; d = ei[N_EDGES + e]; }
    else             { s = d = e - N_EDGES; }
    int p = atomicAdd(&pos[d], 1);
    adj[p] = make_int2(s, e);
}

// ================= batched GEMMs ===========================================
// H1 = x@W1, XL1 = x@lin1_w; 8 nodes per block, 256 threads = output cols
__global__ void gemm1_kernel(const float* __restrict__ x,
                             const float* __restrict__ W1,
                             const float* __restrict__ L1,
                             float* __restrict__ H1, float* __restrict__ XL1) {
    __shared__ float xs[NB][IN_CH];
    int n0 = blockIdx.x * NB;
    int j = threadIdx.x;
    for (int t = j; t < NB * IN_CH; t += 256)
        xs[t >> 7][t & 127] = x[(size_t)(n0 + (t >> 7)) * IN_CH + (t & 127)];
    __syncthreads();
    float a1[NB], a2[NB];
#pragma unroll
    for (int b = 0; b < NB; ++b) { a1[b] = 0.f; a2[b] = 0.f; }
    for (int k = 0; k < IN_CH; ++k) {
        float w1 = W1[k * HC + j], w2 = L1[k * HC + j];
#pragma unroll
        for (int b = 0; b < NB; ++b) {
            a1[b] += xs[b][k] * w1;
            a2[b] += xs[b][k] * w2;
        }
    }
#pragma unroll
    for (int b = 0; b < NB; ++b) {
        H1[(size_t)(n0 + b) * HC + j] = a1[b];
        XL1[(size_t)(n0 + b) * HC + j] = a2[b];
    }
}

// H2 = h@W2 (thr 0..127), XL2 = h@lin2_w (thr 128..255); 8 nodes per block
__global__ void gemm2_kernel(const float* __restrict__ h,
                             const float* __restrict__ W2,
                             const float* __restrict__ L2,
                             float* __restrict__ H2, float* __restrict__ XL2) {
    __shared__ float hs[NB][HC];
    int n0 = blockIdx.x * NB;
    int j = threadIdx.x;
    for (int t = j; t < NB * HC; t += 256)
        hs[t >> 8][t & 255] = h[(size_t)(n0 + (t >> 8)) * HC + (t & 255)];
    __syncthreads();
    bool isH2 = j < OUT_CH;
    const float* Wp = isH2 ? W2 : L2;
    int col = isH2 ? j : j - OUT_CH;
    float acc[NB];
#pragma unroll
    for (int b = 0; b < NB; ++b) acc[b] = 0.f;
    for (int k = 0; k < HC; ++k) {
        float w = Wp[k * OUT_CH + col];
#pragma unroll
        for (int b = 0; b < NB; ++b) acc[b] += hs[b][k] * w;
    }
#pragma unroll
    for (int b = 0; b < NB; ++b) {
        if (isH2) H2[(size_t)(n0 + b) * OUT_CH + col] = acc[b];
        else      XL2[(size_t)(n0 + b) * OUT_CH + col] = acc[b];
    }
}

// ================= attention dot products ==================================
// layer 1: one wave per node, 4 heads; lane l covers channel l of each head
__global__ void att1_kernel(const float* __restrict__ H1,
                            const float* __restrict__ as,
                            const float* __restrict__ ad,
                            float* __restrict__ AS, float* __restrict__ AD) {
    int n = blockIdx.x * 4 + (threadIdx.x >> 6);
    int l = threadIdx.x & 63;
    if (n >= N_NODES) return;
    const float* h = H1 + (size_t)n * HC;
    float vs[HEADS], vd[HEADS];
#pragma unroll
    for (int hh = 0; hh < HEADS; ++hh) {
        float v = h[hh * HID + l];
        vs[hh] = v * as[hh * HID + l];
        vd[hh] = v * ad[hh * HID + l];
    }
#pragma unroll
    for (int off = 32; off; off >>= 1)
#pragma unroll
        for (int hh = 0; hh < HEADS; ++hh) {
            vs[hh] += __shfl_down(vs[hh], off, 64);
            vd[hh] += __shfl_down(vd[hh], off, 64);
        }
    if (l == 0)
#pragma unroll
        for (int hh = 0; hh < HEADS; ++hh) {
            AS[n * HEADS + hh] = vs[hh];
            AD[n * HEADS + hh] = vd[hh];
        }
}

// layer 2: one wave per node, 1 head over 128 channels
__global__ void att2_kernel(const float* __restrict__ H2,
                            const float* __restrict__ as2,
                            const float* __restrict__ ad2,
                            float* __restrict__ AS, float* __restrict__ AD) {
    int n = blockIdx.x * 4 + (threadIdx.x >> 6);
    int l = threadIdx.x & 63;
    if (n >= N_NODES) return;
    const float* h = H2 + (size_t)n * OUT_CH;
    float v0 = h[l], v1 = h[64 + l];
    float vs = v0 * as2[l] + v1 * as2[64 + l];
    float vd = v0 * ad2[l] + v1 * ad2[64 + l];
#pragma unroll
    for (int off = 32; off; off >>= 1) {
        vs += __shfl_down(vs, off, 64);
        vd += __shfl_down(vd, off, 64);
    }
    if (l == 0) { AS[n] = vs; AD[n] = vd; }
}

// ================= edge softmax (atomic max + sum, unchanged) ==============
template <int H>
__global__ void edge_max_kernel(const int* __restrict__ ei,
                                const float* __restrict__ AS,
                                const float* __restrict__ AD,
                                float* __restrict__ EL,
                                unsigned* __restrict__ M) {
    long idx = (long)blockIdx.x * blockDim.x + threadIdx.x;
    if (idx >= (long)EP * H) return;
    int e = (int)(idx / H), hh = (int)(idx % H);
    int s, d;
    if (e < N_EDGES) { s = ei[e]; d = ei[N_EDGES + e]; }
    else             { s = d = e - N_EDGES; }
    float v = AS[s * H + hh] + AD[d * H + hh];
    v = v > 0.f ? v : NEG_SLOPE * v;
    EL[idx] = v;
    atomicMax(&M[d * H + hh], f2o(v));
}

template <int H>
__global__ void edge_sum_kernel(const int* __restrict__ ei,
                                const unsigned* __restrict__ M,
                                float* __restrict__ EL,
                                float* __restrict__ S) {
    long idx = (long)blockIdx.x * blockDim.x + threadIdx.x;
    if (idx >= (long)EP * H) return;
    int e = (int)(idx / H), hh = (int)(idx % H);
    int d = (e < N_EDGES) ? ei[N_EDGES + e] : e - N_EDGES;
    float m = o2f(M[d * H + hh]);
    float el = expf(EL[idx] - m);
    EL[idx] = el;
    atomicAdd(&S[d * H + hh], el);
}

// ================= CSR gather aggregation (no atomics) =====================
// layer 1: block per dst node, 256 threads; fused +XL1+biases+ELU -> HB
__global__ void gather1_kernel(const int* __restrict__ row,
                               const int2* __restrict__ adj,
                               const float* __restrict__ EL,
                               const float* __restrict__ S,
                               const float* __restrict__ H1,
                               const float* __restrict__ XL1,
                               const float* __restrict__ b1,
                               const float* __restrict__ l1b,
                               float* __restrict__ HB) {
    int d = blockIdx.x, j = threadIdx.x, hh = j >> 6;
    int i = row[d], end = row[d + 1];
    float invS = 1.f / (S[d * HEADS + hh] + 1e-16f);
    float acc = 0.f;
    int2 a_next = (i < end) ? adj[i] : make_int2(0, 0);
    for (; i < end;) {
        int2 a = a_next;
        ++i;
        if (i < end) a_next = adj[i];
        acc += EL[(size_t)a.y * HEADS + hh] * H1[(size_t)a.x * HC + j];
    }
    acc *= invS;
    float v = acc + XL1[(size_t)d * HC + j] + b1[j] + l1b[j];
    HB[(size_t)d * HC + j] = v > 0.f ? v : expm1f(v);
}

// layer 2: block per dst node, 128 threads; fused +XL2+biases -> out
__global__ void gather2_kernel(const int* __restrict__ row,
                               const int2* __restrict__ adj,
                               const float* __restrict__ EL,
                               const float* __restrict__ S,
                               const float* __restrict__ H2,
                               const float* __restrict__ XL2,
                               const float* __restrict__ b2,
                               const float* __restrict__ l2b,
                               float* __restrict__ out) {
    int d = blockIdx.x, j = threadIdx.x;
    int i = row[d], end = row[d + 1];
    float invS = 1.f / (S[d] + 1e-16f);
    float acc = 0.f;
    int2 a_next = (i < end) ? adj[i] : make_int2(0, 0);
    for (; i < end;) {
        int2 a = a_next;
        ++i;
        if (i < end) a_next = adj[i];
        acc += EL[a.y] * H2[(size_t)a.x * OUT_CH + j];
    }
    out[(size_t)d * OUT_CH + j] = acc * invS + XL2[(size_t)d * OUT_CH + j]
                                 + b2[j] + l2b[j];
}

extern "C" void kernel_launch(void* const* d_in, const int* in_sizes, int n_in,
                              void* d_out, int out_size, void* d_ws, size_t ws_size,
                              hipStream_t stream) {
    const float* x    = (const float*)d_in[0];
    const int*   ei   = (const int*)d_in[1];
    const float* W1   = (const float*)d_in[2];
    const float* as1  = (const float*)d_in[3];
    const float* ad1  = (const float*)d_in[4];
    const float* b1   = (const float*)d_in[5];
    const float* l1w  = (const float*)d_in[6];
    const float* l1b  = (const float*)d_in[7];
    const float* W2   = (const float*)d_in[8];
    const float* as2  = (const float*)d_in[9];
    const float* ad2  = (const float*)d_in[10];
    const float* b2   = (const float*)d_in[11];
    const float* l2w  = (const float*)d_in[12];
    const float* l2b  = (const float*)d_in[13];
    float* out = (float*)d_out;

    // workspace layout
    float* ws   = (float*)d_ws;
    float* H1   = ws;                          // N*256
    float* XL1  = H1 + (size_t)N_NODES * HC;   // N*256
    float* HB   = XL1 + (size_t)N_NODES * HC;  // N*256 (h after layer 1)
    float* EL   = HB + (size_t)N_NODES * HC;   // EP*4
    float* AS1  = EL + (size_t)EP * HEADS;     // N*4
    float* AD1  = AS1 + (size_t)N_NODES * HEADS;
    unsigned* M1 = (unsigned*)(AD1 + (size_t)N_NODES * HEADS); // N*4
    float* S1   = (float*)(M1 + (size_t)N_NODES * HEADS);      // N*4
    int* cnt    = (int*)(S1 + (size_t)N_NODES * HEADS);        // N
    int* row    = cnt + N_NODES;               // N+1
    int* pos    = row + N_NODES + 1;           // N
    int2* adj   = (int2*)(pos + N_NODES + 1);  // EP pairs
    // layer-2 aliases
    float* H2   = H1;                              // N*128
    float* XL2  = H1 + (size_t)N_NODES * OUT_CH;   // N*128
    float* EL2  = EL;
    float* AS2  = AS1; float* AD2 = AD1;
    unsigned* M2 = M1; float* S2 = S1;

    int nE = (EP + 255) / 256;
    int nEH = (EP * HEADS + 255) / 256;

    // ---- CSR build (topology shared by both layers) ----
    hipMemsetAsync(cnt, 0, N_NODES * 4, stream);
    hist_kernel<<<nE, 256, 0, stream>>>(ei, cnt);
    scan_kernel<<<1, 1024, 0, stream>>>(cnt, row, pos);
    scatter_kernel<<<nE, 256, 0, stream>>>(ei, pos, adj);

    // ---- layer 1 ----
    hipMemsetAsync(M1, 0, (size_t)N_NODES * HEADS * 4, stream);
    hipMemsetAsync(S1, 0, (size_t)N_NODES * HEADS * 4, stream);
    gemm1_kernel<<<N_NODES / NB, 256, 0, stream>>>(x, W1, l1w, H1, XL1);
    att1_kernel<<<(N_NODES + 3) / 4, 256, 0, stream>>>(H1, as1, ad1, AS1, AD1);
    edge_max_kernel<HEADS><<<nEH, 256, 0, stream>>>(ei, AS1, AD1, EL, M1);
    edge_sum_kernel<HEADS><<<nEH, 256, 0, stream>>>(ei, M1, EL, S1);
    gather1_kernel<<<N_NODES, 256, 0, stream>>>(row, adj, EL, S1, H1, XL1, b1, l1b, HB);

    // ---- layer 2 ----
    hipMemsetAsync(M2, 0, (size_t)N_NODES * 4, stream);
    hipMemsetAsync(S2, 0, (size_t)N_NODES * 4, stream);
    gemm2_kernel<<<N_NODES / NB, 256, 0, stream>>>(HB, W2, l2w, H2, XL2);
    att2_kernel<<<(N_NODES + 3) / 4, 256, 0, stream>>>(H2, as2, ad2, AS2, AD2);
    edge_max_kernel<1><<<nE, 256, 0, stream>>>(ei, AS2, AD2, EL2, M2);
    edge_sum_kernel<1><<<nE, 256, 0, stream>>>(ei, M2, EL2, S2);
    gather2_kernel<<<N_NODES, 128, 0, stream>>>(row, adj, EL2, S2, H2, XL2, b2, l2b, out);
}

// Round 3
// 506.871 us; speedup vs baseline: 4.0975x; 1.8486x over previous
//
#include <hip/hip_runtime.h>
#include <math.h>

#define N_NODES 50000
#define N_EDGES 800000
#define EP (N_EDGES + N_NODES)   /* 850000 edges incl. self-loops */
#define IN_CH 128
#define HID 64
#define HEADS 4
#define HC (HID * HEADS)         /* 256 */
#define OUT_CH 128
#define NEG_SLOPE 0.2f
#define NB 16                     /* nodes per GEMM block */
#define NSCAN ((N_NODES + 255) / 256)   /* 196 */

__device__ __forceinline__ float bf2f(unsigned short u) {
    return __uint_as_float(((unsigned)u) << 16);
}
__device__ __forceinline__ unsigned short f2bf(float f) {
    unsigned u = __float_as_uint(f);
    return (unsigned short)((u + 0x7fffu + ((u >> 16) & 1u)) >> 16);
}
__device__ __forceinline__ float2 bf2f2(ushort2 q) {
    return make_float2(bf2f(q.x), bf2f(q.y));
}
__device__ __forceinline__ float lrelu(float v) {
    return v > 0.f ? v : NEG_SLOPE * v;
}

// ================= CSR build (topology only, shared by both layers) ========
__global__ void hist_kernel(const int* __restrict__ ei, int* __restrict__ cnt) {
    int e = blockIdx.x * 256 + threadIdx.x;
    if (e >= EP) return;
    int d = (e < N_EDGES) ? ei[N_EDGES + e] : e - N_EDGES;
    atomicAdd(&cnt[d], 1);
}

// phase 1: per-256-chunk local exclusive scan -> row (local), bsum
__global__ void scan1_kernel(const int* __restrict__ cnt,
                             int* __restrict__ row, int* __restrict__ bsum) {
    __shared__ int buf[256];
    int i = blockIdx.x * 256 + threadIdx.x;
    int v = (i < N_NODES) ? cnt[i] : 0;
    buf[threadIdx.x] = v;
    __syncthreads();
#pragma unroll
    for (int off = 1; off < 256; off <<= 1) {
        int t = (threadIdx.x >= off) ? buf[threadIdx.x - off] : 0;
        __syncthreads();
        buf[threadIdx.x] += t;
        __syncthreads();
    }
    if (i < N_NODES) row[i] = buf[threadIdx.x] - v;   // local exclusive
    if (threadIdx.x == 255) bsum[blockIdx.x] = buf[255];
}

// phase 2: scan the 196 block sums; write grand total to rowN (= row+N)
__global__ void scan2_kernel(const int* __restrict__ bsum,
                             int* __restrict__ boff, int* __restrict__ rowN) {
    __shared__ int buf[256];
    int tid = threadIdx.x;
    int v = (tid < NSCAN) ? bsum[tid] : 0;
    buf[tid] = v;
    __syncthreads();
#pragma unroll
    for (int off = 1; off < 256; off <<= 1) {
        int t = (tid >= off) ? buf[tid - off] : 0;
        __syncthreads();
        buf[tid] += t;
        __syncthreads();
    }
    if (tid < NSCAN) boff[tid] = buf[tid] - v;        // exclusive
    if (tid == 255) rowN[0] = buf[255];
}

// phase 3: add block offsets; init pos
__global__ void scan3_kernel(int* __restrict__ row, const int* __restrict__ boff,
                             int* __restrict__ pos) {
    int i = blockIdx.x * 256 + threadIdx.x;
    if (i >= N_NODES) return;
    int r = row[i] + boff[blockIdx.x];
    row[i] = r;
    pos[i] = r;
}

__global__ void scatter_kernel(const int* __restrict__ ei,
                               int* __restrict__ pos, int* __restrict__ adjS) {
    int e = blockIdx.x * 256 + threadIdx.x;
    if (e >= EP) return;
    int s, d;
    if (e < N_EDGES) { s = ei[e]; d = ei[N_EDGES + e]; }
    else             { s = d = e - N_EDGES; }
    int p = atomicAdd(&pos[d], 1);
    adjS[p] = s;
}

// ================= GEMM 1: H1b(bf16) = x@W1, XL1 = x@lin1_w, + att dots ====
__global__ void gemm1_kernel(const float* __restrict__ x,
                             const float* __restrict__ W1,
                             const float* __restrict__ L1,
                             const float* __restrict__ as1,
                             const float* __restrict__ ad1,
                             unsigned short* __restrict__ H1b,
                             float* __restrict__ XL1,
                             float* __restrict__ AS, float* __restrict__ AD) {
    __shared__ float xs[NB][IN_CH];
    int n0 = blockIdx.x * NB;
    int j = threadIdx.x;
    for (int t = j; t < NB * IN_CH; t += 256)
        xs[t >> 7][t & 127] = x[(size_t)(n0 + (t >> 7)) * IN_CH + (t & 127)];
    __syncthreads();
    float a1[NB], a2[NB];
#pragma unroll
    for (int b = 0; b < NB; ++b) { a1[b] = 0.f; a2[b] = 0.f; }
    for (int k = 0; k < IN_CH; ++k) {
        float w1 = W1[k * HC + j], w2 = L1[k * HC + j];
#pragma unroll
        for (int b = 0; b < NB; ++b) {
            a1[b] += xs[b][k] * w1;
            a2[b] += xs[b][k] * w2;
        }
    }
    int l = j & 63, w = j >> 6;                 // w = head
    float s_att = as1[w * HID + l], d_att = ad1[w * HID + l];
#pragma unroll
    for (int b = 0; b < NB; ++b) {
        H1b[(size_t)(n0 + b) * HC + j] = f2bf(a1[b]);
        XL1[(size_t)(n0 + b) * HC + j] = a2[b];
    }
#pragma unroll
    for (int b = 0; b < NB; ++b) {
        float vs = a1[b] * s_att, vd = a1[b] * d_att;
#pragma unroll
        for (int off = 32; off; off >>= 1) {
            vs += __shfl_down(vs, off, 64);
            vd += __shfl_down(vd, off, 64);
        }
        if (l == 0) {
            AS[(n0 + b) * HEADS + w] = vs;
            AD[(n0 + b) * HEADS + w] = vd;
        }
    }
}

// ================= GEMM 2: H2b(bf16) = h@W2, XL2 = h@lin2_w, + att dots ====
__global__ void gemm2_kernel(const float* __restrict__ h,
                             const float* __restrict__ W2,
                             const float* __restrict__ L2,
                             const float* __restrict__ as2,
                             const float* __restrict__ ad2,
                             unsigned short* __restrict__ H2b,
                             float* __restrict__ XL2,
                             float* __restrict__ AS, float* __restrict__ AD) {
    __shared__ float hs[NB][HC];
    __shared__ float redS[2][NB], redD[2][NB];
    int n0 = blockIdx.x * NB;
    int j = threadIdx.x;
    for (int t = j; t < NB * HC; t += 256)
        hs[t >> 8][t & 255] = h[(size_t)(n0 + (t >> 8)) * HC + (t & 255)];
    __syncthreads();
    bool isH2 = j < OUT_CH;
    const float* Wp = isH2 ? W2 : L2;
    int col = isH2 ? j : j - OUT_CH;
    float acc[NB];
#pragma unroll
    for (int b = 0; b < NB; ++b) acc[b] = 0.f;
    for (int k = 0; k < HC; ++k) {
        float wv = Wp[k * OUT_CH + col];
#pragma unroll
        for (int b = 0; b < NB; ++b) acc[b] += hs[b][k] * wv;
    }
    int l = j & 63, w = j >> 6;
    float sa = as2[col], da = ad2[col];
#pragma unroll
    for (int b = 0; b < NB; ++b) {
        if (isH2) H2b[(size_t)(n0 + b) * OUT_CH + col] = f2bf(acc[b]);
        else      XL2[(size_t)(n0 + b) * OUT_CH + col] = acc[b];
    }
#pragma unroll
    for (int b = 0; b < NB; ++b) {
        float vs = acc[b] * sa, vd = acc[b] * da;
#pragma unroll
        for (int off = 32; off; off >>= 1) {
            vs += __shfl_down(vs, off, 64);
            vd += __shfl_down(vd, off, 64);
        }
        if (l == 0 && w < 2) { redS[w][b] = vs; redD[w][b] = vd; }
    }
    __syncthreads();
    if (j < NB)               AS[n0 + j] = redS[0][j] + redS[1][j];
    else if (j < 2 * NB)      AD[n0 + j - NB] = redD[0][j - NB] + redD[1][j - NB];
}

// ======= fused gather layer 1: softmax + aggregate + skip + bias + ELU =====
// block = 128 threads, one dst node; thread j covers channels 2j,2j+1
__global__ void gather1_kernel(const int* __restrict__ row,
                               const int* __restrict__ adjS,
                               const float* __restrict__ AS,
                               const float* __restrict__ AD,
                               const unsigned short* __restrict__ H1b,
                               const float* __restrict__ XL1,
                               const float* __restrict__ b1,
                               const float* __restrict__ l1b,
                               float* __restrict__ HB) {
    int d = blockIdx.x, j = threadIdx.x;
    int hh = j >> 5;                        // head of channels 2j,2j+1
    int beg = row[d], end = row[d + 1];
    float advd = AD[d * HEADS + hh];
    const ushort2* Hr = (const ushort2*)H1b;
    float ax = 0.f, ay = 0.f, esum = 0.f;
    int i = beg;
    for (; i + 4 <= end; i += 4) {
        int s0 = adjS[i], s1 = adjS[i + 1], s2 = adjS[i + 2], s3 = adjS[i + 3];
        float as0 = AS[s0 * HEADS + hh], as1v = AS[s1 * HEADS + hh];
        float as2v = AS[s2 * HEADS + hh], as3v = AS[s3 * HEADS + hh];
        ushort2 q0 = Hr[(size_t)s0 * 128 + j];
        ushort2 q1 = Hr[(size_t)s1 * 128 + j];
        ushort2 q2 = Hr[(size_t)s2 * 128 + j];
        ushort2 q3 = Hr[(size_t)s3 * 128 + j];
        float e0 = expf(lrelu(as0 + advd));
        float e1 = expf(lrelu(as1v + advd));
        float e2 = expf(lrelu(as2v + advd));
        float e3 = expf(lrelu(as3v + advd));
        float2 h0 = bf2f2(q0), h1 = bf2f2(q1), h2 = bf2f2(q2), h3 = bf2f2(q3);
        ax += e0 * h0.x + e1 * h1.x + e2 * h2.x + e3 * h3.x;
        ay += e0 * h0.y + e1 * h1.y + e2 * h2.y + e3 * h3.y;
        esum += e0 + e1 + e2 + e3;
    }
    for (; i < end; ++i) {
        int s = adjS[i];
        float e = expf(lrelu(AS[s * HEADS + hh] + advd));
        float2 hv = bf2f2(Hr[(size_t)s * 128 + j]);
        ax += e * hv.x; ay += e * hv.y; esum += e;
    }
    float inv = 1.f / (esum + 1e-16f);
    float2 xl = ((const float2*)XL1)[(size_t)d * 128 + j];
    float2 bb = ((const float2*)b1)[j];
    float2 lb = ((const float2*)l1b)[j];
    float v0 = ax * inv + xl.x + bb.x + lb.x;
    float v1 = ay * inv + xl.y + bb.y + lb.y;
    v0 = v0 > 0.f ? v0 : expm1f(v0);
    v1 = v1 > 0.f ? v1 : expm1f(v1);
    ((float2*)HB)[(size_t)d * 128 + j] = make_float2(v0, v1);
}

// ======= fused gather layer 2: softmax + aggregate + skip + bias -> out ====
// block = 64 threads, one dst node; thread l covers channels 2l,2l+1
__global__ void gather2_kernel(const int* __restrict__ row,
                               const int* __restrict__ adjS,
                               const float* __restrict__ AS,
                               const float* __restrict__ AD,
                               const unsigned short* __restrict__ H2b,
                               const float* __restrict__ XL2,
                               const float* __restrict__ b2,
                               const float* __restrict__ l2b,
                               float* __restrict__ out) {
    int d = blockIdx.x, l = threadIdx.x;
    int beg = row[d], end = row[d + 1];
    float advd = AD[d];
    const ushort2* Hr = (const ushort2*)H2b;
    float ax = 0.f, ay = 0.f, esum = 0.f;
    int i = beg;
    for (; i + 4 <= end; i += 4) {
        int s0 = adjS[i], s1 = adjS[i + 1], s2 = adjS[i + 2], s3 = adjS[i + 3];
        float as0 = AS[s0], as1v = AS[s1], as2v = AS[s2], as3v = AS[s3];
        ushort2 q0 = Hr[(size_t)s0 * 64 + l];
        ushort2 q1 = Hr[(size_t)s1 * 64 + l];
        ushort2 q2 = Hr[(size_t)s2 * 64 + l];
        ushort2 q3 = Hr[(size_t)s3 * 64 + l];
        float e0 = expf(lrelu(as0 + advd));
        float e1 = expf(lrelu(as1v + advd));
        float e2 = expf(lrelu(as2v + advd));
        float e3 = expf(lrelu(as3v + advd));
        float2 h0 = bf2f2(q0), h1 = bf2f2(q1), h2 = bf2f2(q2), h3 = bf2f2(q3);
        ax += e0 * h0.x + e1 * h1.x + e2 * h2.x + e3 * h3.x;
        ay += e0 * h0.y + e1 * h1.y + e2 * h2.y + e3 * h3.y;
        esum += e0 + e1 + e2 + e3;
    }
    for (; i < end; ++i) {
        int s = adjS[i];
        float e = expf(lrelu(AS[s] + advd));
        float2 hv = bf2f2(Hr[(size_t)s * 64 + l]);
        ax += e * hv.x; ay += e * hv.y; esum += e;
    }
    float inv = 1.f / (esum + 1e-16f);
    float2 xl = ((const float2*)XL2)[(size_t)d * 64 + l];
    float2 bb = ((const float2*)b2)[l];
    float2 lb = ((const float2*)l2b)[l];
    ((float2*)out)[(size_t)d * 64 + l] =
        make_float2(ax * inv + xl.x + bb.x + lb.x,
                    ay * inv + xl.y + bb.y + lb.y);
}

extern "C" void kernel_launch(void* const* d_in, const int* in_sizes, int n_in,
                              void* d_out, int out_size, void* d_ws, size_t ws_size,
                              hipStream_t stream) {
    const float* x    = (const float*)d_in[0];
    const int*   ei   = (const int*)d_in[1];
    const float* W1   = (const float*)d_in[2];
    const float* as1  = (const float*)d_in[3];
    const float* ad1  = (const float*)d_in[4];
    const float* b1   = (const float*)d_in[5];
    const float* l1w  = (const float*)d_in[6];
    const float* l1b  = (const float*)d_in[7];
    const float* W2   = (const float*)d_in[8];
    const float* as2  = (const float*)d_in[9];
    const float* ad2  = (const float*)d_in[10];
    const float* b2   = (const float*)d_in[11];
    const float* l2w  = (const float*)d_in[12];
    const float* l2b  = (const float*)d_in[13];
    float* out = (float*)d_out;

    // workspace layout (float units)
    float* ws = (float*)d_ws;
    unsigned short* H1b = (unsigned short*)ws;              // N*256 bf16 = N*128 f
    float* XL1 = ws + (size_t)N_NODES * 128;                // N*256
    float* HB  = XL1 + (size_t)N_NODES * HC;                // N*256
    float* AS1 = HB + (size_t)N_NODES * HC;                 // N*4
    float* AD1 = AS1 + (size_t)N_NODES * HEADS;             // N*4
    float* AS2 = AD1 + (size_t)N_NODES * HEADS;             // N
    float* AD2 = AS2 + N_NODES;                             // N
    int* cnt   = (int*)(AD2 + N_NODES);                     // N
    int* row   = cnt + N_NODES;                             // N+1
    int* pos   = row + N_NODES + 1;                         // N
    int* bsum  = pos + N_NODES;                             // NSCAN
    int* boff  = bsum + NSCAN;                              // NSCAN
    int* adjS  = boff + NSCAN;                              // EP
    // layer-2 aliases (written after their layer-1 uses complete)
    unsigned short* H2b = H1b;                              // N*128 bf16
    float* XL2 = XL1;                                       // N*128

    int nE = (EP + 255) / 256;

    // ---- CSR build (shared topology) ----
    hipMemsetAsync(cnt, 0, N_NODES * 4, stream);
    hist_kernel<<<nE, 256, 0, stream>>>(ei, cnt);
    scan1_kernel<<<NSCAN, 256, 0, stream>>>(cnt, row, bsum);
    scan2_kernel<<<1, 256, 0, stream>>>(bsum, boff, row + N_NODES);
    scan3_kernel<<<NSCAN, 256, 0, stream>>>(row, boff, pos);
    scatter_kernel<<<nE, 256, 0, stream>>>(ei, pos, adjS);

    // ---- layer 1 ----
    gemm1_kernel<<<N_NODES / NB, 256, 0, stream>>>(x, W1, l1w, as1, ad1,
                                                   H1b, XL1, AS1, AD1);
    gather1_kernel<<<N_NODES, 128, 0, stream>>>(row, adjS, AS1, AD1, H1b, XL1,
                                                b1, l1b, HB);

    // ---- layer 2 ----
    gemm2_kernel<<<N_NODES / NB, 256, 0, stream>>>(HB, W2, l2w, as2, ad2,
                                                   H2b, XL2, AS2, AD2);
    gather2_kernel<<<N_NODES, 64, 0, stream>>>(row, adjS, AS2, AD2, H2b, XL2,
                                               b2, l2b, out);
}

// Round 4
// 324.279 us; speedup vs baseline: 6.4047x; 1.5631x over previous
//
#include <hip/hip_runtime.h>
#include <math.h>

#define N_NODES 50000
#define N_EDGES 800000
#define EP (N_EDGES + N_NODES)   /* 850000 edges incl. self-loops */
#define IN_CH 128
#define HID 64
#define HEADS 4
#define HC (HID * HEADS)         /* 256 */
#define OUT_CH 128
#define NEG_SLOPE 0.2f
#define NSCAN ((N_NODES + 255) / 256)   /* 196 */
#define MTILES (N_NODES / 16)           /* 3125, exact */

typedef __bf16 bf16x8 __attribute__((ext_vector_type(8)));
typedef float  f32x4  __attribute__((ext_vector_type(4)));

__device__ __forceinline__ float bf2f(unsigned short u) {
    return __uint_as_float(((unsigned)u) << 16);
}
__device__ __forceinline__ unsigned short f2bf(float f) {
    unsigned u = __float_as_uint(f);
    return (unsigned short)((u + 0x7fffu + ((u >> 16) & 1u)) >> 16);
}
__device__ __forceinline__ float2 bf2f2(ushort2 q) {
    return make_float2(bf2f(q.x), bf2f(q.y));
}
__device__ __forceinline__ float lrelu(float v) {
    return v > 0.f ? v : NEG_SLOPE * v;
}
__device__ __forceinline__ bf16x8 ldfrag(const unsigned short* p) {
    uint4 u = *(const uint4*)p;
    return __builtin_bit_cast(bf16x8, u);
}

// ================= CSR build (topology only, shared by both layers) ========
__global__ void hist_kernel(const int* __restrict__ ei, int* __restrict__ cnt) {
    int e = blockIdx.x * 256 + threadIdx.x;
    if (e >= EP) return;
    int d = (e < N_EDGES) ? ei[N_EDGES + e] : e - N_EDGES;
    atomicAdd(&cnt[d], 1);
}

__global__ void scan1_kernel(const int* __restrict__ cnt,
                             int* __restrict__ row, int* __restrict__ bsum) {
    __shared__ int buf[256];
    int i = blockIdx.x * 256 + threadIdx.x;
    int v = (i < N_NODES) ? cnt[i] : 0;
    buf[threadIdx.x] = v;
    __syncthreads();
#pragma unroll
    for (int off = 1; off < 256; off <<= 1) {
        int t = (threadIdx.x >= off) ? buf[threadIdx.x - off] : 0;
        __syncthreads();
        buf[threadIdx.x] += t;
        __syncthreads();
    }
    if (i < N_NODES) row[i] = buf[threadIdx.x] - v;   // local exclusive
    if (threadIdx.x == 255) bsum[blockIdx.x] = buf[255];
}

__global__ void scan2_kernel(const int* __restrict__ bsum,
                             int* __restrict__ boff, int* __restrict__ rowN) {
    __shared__ int buf[256];
    int tid = threadIdx.x;
    int v = (tid < NSCAN) ? bsum[tid] : 0;
    buf[tid] = v;
    __syncthreads();
#pragma unroll
    for (int off = 1; off < 256; off <<= 1) {
        int t = (tid >= off) ? buf[tid - off] : 0;
        __syncthreads();
        buf[tid] += t;
        __syncthreads();
    }
    if (tid < NSCAN) boff[tid] = buf[tid] - v;        // exclusive
    if (tid == 255) rowN[0] = buf[255];
}

__global__ void scan3_kernel(int* __restrict__ row, const int* __restrict__ boff,
                             int* __restrict__ pos) {
    int i = blockIdx.x * 256 + threadIdx.x;
    if (i >= N_NODES) return;
    int r = row[i] + boff[blockIdx.x];
    row[i] = r;
    pos[i] = r;
}

__global__ void scatter_kernel(const int* __restrict__ ei,
                               int* __restrict__ pos, int* __restrict__ adjS) {
    int e = blockIdx.x * 256 + threadIdx.x;
    if (e >= EP) return;
    int s, d;
    if (e < N_EDGES) { s = ei[e]; d = ei[N_EDGES + e]; }
    else             { s = d = e - N_EDGES; }
    int p = atomicAdd(&pos[d], 1);
    adjS[p] = s;
}

// ================= bf16 conversion + weight packing ========================
__global__ void convx_kernel(const float* __restrict__ x,
                             unsigned short* __restrict__ xb) {
    int i = blockIdx.x * 256 + threadIdx.x;      // 4 elems per thread
    if (i >= N_NODES * (IN_CH / 4)) return;
    float4 v = ((const float4*)x)[i];
    ushort4 o;
    o.x = f2bf(v.x); o.y = f2bf(v.y); o.z = f2bf(v.z); o.w = f2bf(v.w);
    ((ushort4*)xb)[i] = o;
}

// pack [W1 | lin1_w] (128x512) into MFMA B-fragment lane order
// frag = ks*32 + nf (ks: k-step of 32, nf: 16-col group); 8 bf16 per lane
__global__ void pack1_kernel(const float* __restrict__ W1,
                             const float* __restrict__ L1,
                             unsigned short* __restrict__ Bp) {
    int t = blockIdx.x * 256 + threadIdx.x;      // 128 frags * 64 lanes
    if (t >= 128 * 64) return;
    int frag = t >> 6, l = t & 63;
    int ks = frag >> 5, nf = frag & 31;
    int col = nf * 16 + (l & 15);
    int kb = ks * 32 + (l >> 4) * 8;
    unsigned short* o = Bp + (size_t)t * 8;
#pragma unroll
    for (int i = 0; i < 8; ++i) {
        int k = kb + i;
        float v = (col < HC) ? W1[k * HC + col] : L1[k * HC + (col - HC)];
        o[i] = f2bf(v);
    }
}

// pack [W2 | lin2_w] (256x256); frag = ks*16 + nf, ks 0..7, nf 0..15
__global__ void pack2_kernel(const float* __restrict__ W2,
                             const float* __restrict__ L2,
                             unsigned short* __restrict__ Bp) {
    int t = blockIdx.x * 256 + threadIdx.x;
    if (t >= 128 * 64) return;
    int frag = t >> 6, l = t & 63;
    int ks = frag >> 4, nf = frag & 15;
    int col = nf * 16 + (l & 15);
    int kb = ks * 32 + (l >> 4) * 8;
    unsigned short* o = Bp + (size_t)t * 8;
#pragma unroll
    for (int i = 0; i < 8; ++i) {
        int k = kb + i;
        float v = (col < OUT_CH) ? W2[k * OUT_CH + col]
                                 : L2[k * OUT_CH + (col - OUT_CH)];
        o[i] = f2bf(v);
    }
}

// ================= MFMA GEMM 1: [H1b | XL1] = xb @ [W1 | lin1_w] ===========
// grid 3125 (16-row tiles), 4 waves; wave w owns cols [w*128, w*128+128)
__global__ __launch_bounds__(256) void gemm1_mfma(
        const unsigned short* __restrict__ xb,
        const unsigned short* __restrict__ Bp,
        unsigned short* __restrict__ H1b, float* __restrict__ XL1) {
    int m0 = blockIdx.x * 16;
    int w = threadIdx.x >> 6, l = threadIdx.x & 63;
    int row = m0 + (l & 15);
    int koff = (l >> 4) * 8;
    f32x4 acc[8];
#pragma unroll
    for (int f = 0; f < 8; ++f) acc[f] = (f32x4){0.f, 0.f, 0.f, 0.f};
#pragma unroll
    for (int ks = 0; ks < 4; ++ks) {
        bf16x8 a = ldfrag(xb + (size_t)row * IN_CH + ks * 32 + koff);
        const unsigned short* bb = Bp + ((size_t)((ks * 32 + w * 8) * 64 + l)) * 8;
#pragma unroll
        for (int f = 0; f < 8; ++f) {
            bf16x8 b = ldfrag(bb + (size_t)f * 512);
            acc[f] = __builtin_amdgcn_mfma_f32_16x16x32_bf16(a, b, acc[f], 0, 0, 0);
        }
    }
    int rq = (l >> 4) * 4, lc = l & 15;
#pragma unroll
    for (int f = 0; f < 8; ++f) {
        int col = w * 128 + f * 16 + lc;
#pragma unroll
        for (int r = 0; r < 4; ++r) {
            int m = m0 + rq + r;
            float v = acc[f][r];
            if (col < HC) H1b[(size_t)m * HC + col] = f2bf(v);
            else          XL1[(size_t)m * HC + (col - HC)] = v;
        }
    }
}

// ================= MFMA GEMM 2: [H2b | XL2] = HBb @ [W2 | lin2_w] ==========
// grid 3125, 4 waves; wave w owns cols [w*64, w*64+64)
__global__ __launch_bounds__(256) void gemm2_mfma(
        const unsigned short* __restrict__ HBb,
        const unsigned short* __restrict__ Bp,
        unsigned short* __restrict__ H2b, float* __restrict__ XL2) {
    int m0 = blockIdx.x * 16;
    int w = threadIdx.x >> 6, l = threadIdx.x & 63;
    int row = m0 + (l & 15);
    int koff = (l >> 4) * 8;
    f32x4 acc[4];
#pragma unroll
    for (int f = 0; f < 4; ++f) acc[f] = (f32x4){0.f, 0.f, 0.f, 0.f};
#pragma unroll
    for (int ks = 0; ks < 8; ++ks) {
        bf16x8 a = ldfrag(HBb + (size_t)row * HC + ks * 32 + koff);
        const unsigned short* bb = Bp + ((size_t)((ks * 16 + w * 4) * 64 + l)) * 8;
#pragma unroll
        for (int f = 0; f < 4; ++f) {
            bf16x8 b = ldfrag(bb + (size_t)f * 512);
            acc[f] = __builtin_amdgcn_mfma_f32_16x16x32_bf16(a, b, acc[f], 0, 0, 0);
        }
    }
    int rq = (l >> 4) * 4, lc = l & 15;
#pragma unroll
    for (int f = 0; f < 4; ++f) {
        int col = w * 64 + f * 16 + lc;
#pragma unroll
        for (int r = 0; r < 4; ++r) {
            int m = m0 + rq + r;
            float v = acc[f][r];
            if (col < OUT_CH) H2b[(size_t)m * OUT_CH + col] = f2bf(v);
            else              XL2[(size_t)m * OUT_CH + (col - OUT_CH)] = v;
        }
    }
}

// ================= attention dot products (read bf16 H) ====================
__global__ void att1_kernel(const unsigned short* __restrict__ H1b,
                            const float* __restrict__ as,
                            const float* __restrict__ ad,
                            float* __restrict__ AS, float* __restrict__ AD) {
    int n = blockIdx.x * 4 + (threadIdx.x >> 6);
    int l = threadIdx.x & 63;
    if (n >= N_NODES) return;
    const unsigned short* h = H1b + (size_t)n * HC;
    float vs[HEADS], vd[HEADS];
#pragma unroll
    for (int hh = 0; hh < HEADS; ++hh) {
        float v = bf2f(h[hh * HID + l]);
        vs[hh] = v * as[hh * HID + l];
        vd[hh] = v * ad[hh * HID + l];
    }
#pragma unroll
    for (int off = 32; off; off >>= 1)
#pragma unroll
        for (int hh = 0; hh < HEADS; ++hh) {
            vs[hh] += __shfl_down(vs[hh], off, 64);
            vd[hh] += __shfl_down(vd[hh], off, 64);
        }
    if (l == 0)
#pragma unroll
        for (int hh = 0; hh < HEADS; ++hh) {
            AS[n * HEADS + hh] = vs[hh];
            AD[n * HEADS + hh] = vd[hh];
        }
}

__global__ void att2_kernel(const unsigned short* __restrict__ H2b,
                            const float* __restrict__ as2,
                            const float* __restrict__ ad2,
                            float* __restrict__ AS, float* __restrict__ AD) {
    int n = blockIdx.x * 4 + (threadIdx.x >> 6);
    int l = threadIdx.x & 63;
    if (n >= N_NODES) return;
    const unsigned short* h = H2b + (size_t)n * OUT_CH;
    float v0 = bf2f(h[l]), v1 = bf2f(h[64 + l]);
    float vs = v0 * as2[l] + v1 * as2[64 + l];
    float vd = v0 * ad2[l] + v1 * ad2[64 + l];
#pragma unroll
    for (int off = 32; off; off >>= 1) {
        vs += __shfl_down(vs, off, 64);
        vd += __shfl_down(vd, off, 64);
    }
    if (l == 0) { AS[n] = vs; AD[n] = vd; }
}

// ======= fused gather layer 1: softmax + aggregate + skip + bias + ELU =====
// writes h as bf16 (consumed by MFMA gemm2)
__global__ void gather1_kernel(const int* __restrict__ row,
                               const int* __restrict__ adjS,
                               const float* __restrict__ AS,
                               const float* __restrict__ AD,
                               const unsigned short* __restrict__ H1b,
                               const float* __restrict__ XL1,
                               const float* __restrict__ b1,
                               const float* __restrict__ l1b,
                               unsigned short* __restrict__ HBb) {
    int d = blockIdx.x, j = threadIdx.x;
    int hh = j >> 5;                        // head of channels 2j,2j+1
    int beg = row[d], end = row[d + 1];
    float advd = AD[d * HEADS + hh];
    const ushort2* Hr = (const ushort2*)H1b;
    float ax = 0.f, ay = 0.f, esum = 0.f;
    int i = beg;
    for (; i + 4 <= end; i += 4) {
        int s0 = adjS[i], s1 = adjS[i + 1], s2 = adjS[i + 2], s3 = adjS[i + 3];
        float as0 = AS[s0 * HEADS + hh], as1v = AS[s1 * HEADS + hh];
        float as2v = AS[s2 * HEADS + hh], as3v = AS[s3 * HEADS + hh];
        ushort2 q0 = Hr[(size_t)s0 * 128 + j];
        ushort2 q1 = Hr[(size_t)s1 * 128 + j];
        ushort2 q2 = Hr[(size_t)s2 * 128 + j];
        ushort2 q3 = Hr[(size_t)s3 * 128 + j];
        float e0 = expf(lrelu(as0 + advd));
        float e1 = expf(lrelu(as1v + advd));
        float e2 = expf(lrelu(as2v + advd));
        float e3 = expf(lrelu(as3v + advd));
        float2 h0 = bf2f2(q0), h1 = bf2f2(q1), h2 = bf2f2(q2), h3 = bf2f2(q3);
        ax += e0 * h0.x + e1 * h1.x + e2 * h2.x + e3 * h3.x;
        ay += e0 * h0.y + e1 * h1.y + e2 * h2.y + e3 * h3.y;
        esum += e0 + e1 + e2 + e3;
    }
    for (; i < end; ++i) {
        int s = adjS[i];
        float e = expf(lrelu(AS[s * HEADS + hh] + advd));
        float2 hv = bf2f2(Hr[(size_t)s * 128 + j]);
        ax += e * hv.x; ay += e * hv.y; esum += e;
    }
    float inv = 1.f / (esum + 1e-16f);
    float2 xl = ((const float2*)XL1)[(size_t)d * 128 + j];
    float2 bb = ((const float2*)b1)[j];
    float2 lb = ((const float2*)l1b)[j];
    float v0 = ax * inv + xl.x + bb.x + lb.x;
    float v1 = ay * inv + xl.y + bb.y + lb.y;
    v0 = v0 > 0.f ? v0 : expm1f(v0);
    v1 = v1 > 0.f ? v1 : expm1f(v1);
    ((ushort2*)HBb)[(size_t)d * 128 + j] = make_ushort2(f2bf(v0), f2bf(v1));
}

// ======= fused gather layer 2: softmax + aggregate + skip + bias -> out ====
__global__ void gather2_kernel(const int* __restrict__ row,
                               const int* __restrict__ adjS,
                               const float* __restrict__ AS,
                               const float* __restrict__ AD,
                               const unsigned short* __restrict__ H2b,
                               const float* __restrict__ XL2,
                               const float* __restrict__ b2,
                               const float* __restrict__ l2b,
                               float* __restrict__ out) {
    int d = blockIdx.x, l = threadIdx.x;
    int beg = row[d], end = row[d + 1];
    float advd = AD[d];
    const ushort2* Hr = (const ushort2*)H2b;
    float ax = 0.f, ay = 0.f, esum = 0.f;
    int i = beg;
    for (; i + 4 <= end; i += 4) {
        int s0 = adjS[i], s1 = adjS[i + 1], s2 = adjS[i + 2], s3 = adjS[i + 3];
        float as0 = AS[s0], as1v = AS[s1], as2v = AS[s2], as3v = AS[s3];
        ushort2 q0 = Hr[(size_t)s0 * 64 + l];
        ushort2 q1 = Hr[(size_t)s1 * 64 + l];
        ushort2 q2 = Hr[(size_t)s2 * 64 + l];
        ushort2 q3 = Hr[(size_t)s3 * 64 + l];
        float e0 = expf(lrelu(as0 + advd));
        float e1 = expf(lrelu(as1v + advd));
        float e2 = expf(lrelu(as2v + advd));
        float e3 = expf(lrelu(as3v + advd));
        float2 h0 = bf2f2(q0), h1 = bf2f2(q1), h2 = bf2f2(q2), h3 = bf2f2(q3);
        ax += e0 * h0.x + e1 * h1.x + e2 * h2.x + e3 * h3.x;
        ay += e0 * h0.y + e1 * h1.y + e2 * h2.y + e3 * h3.y;
        esum += e0 + e1 + e2 + e3;
    }
    for (; i < end; ++i) {
        int s = adjS[i];
        float e = expf(lrelu(AS[s] + advd));
        float2 hv = bf2f2(Hr[(size_t)s * 64 + l]);
        ax += e * hv.x; ay += e * hv.y; esum += e;
    }
    float inv = 1.f / (esum + 1e-16f);
    float2 xl = ((const float2*)XL2)[(size_t)d * 64 + l];
    float2 bb = ((const float2*)b2)[l];
    float2 lb = ((const float2*)l2b)[l];
    ((float2*)out)[(size_t)d * 64 + l] =
        make_float2(ax * inv + xl.x + bb.x + lb.x,
                    ay * inv + xl.y + bb.y + lb.y);
}

extern "C" void kernel_launch(void* const* d_in, const int* in_sizes, int n_in,
                              void* d_out, int out_size, void* d_ws, size_t ws_size,
                              hipStream_t stream) {
    const float* x    = (const float*)d_in[0];
    const int*   ei   = (const int*)d_in[1];
    const float* W1   = (const float*)d_in[2];
    const float* as1  = (const float*)d_in[3];
    const float* ad1  = (const float*)d_in[4];
    const float* b1   = (const float*)d_in[5];
    const float* l1w  = (const float*)d_in[6];
    const float* l1b  = (const float*)d_in[7];
    const float* W2   = (const float*)d_in[8];
    const float* as2  = (const float*)d_in[9];
    const float* ad2  = (const float*)d_in[10];
    const float* b2   = (const float*)d_in[11];
    const float* l2w  = (const float*)d_in[12];
    const float* l2b  = (const float*)d_in[13];
    float* out = (float*)d_out;

    // workspace layout (float units)
    float* ws = (float*)d_ws;
    unsigned short* xb  = (unsigned short*)ws;                  // N*128 bf16
    float* fp = ws + (size_t)N_NODES * 64;
    unsigned short* H1b = (unsigned short*)fp;                  // N*256 bf16
    fp += (size_t)N_NODES * 128;
    float* XL1 = fp;                                            // N*256 f32
    fp += (size_t)N_NODES * HC;
    unsigned short* HBb = (unsigned short*)fp;                  // N*256 bf16
    fp += (size_t)N_NODES * 128;
    float* AS1 = fp; fp += (size_t)N_NODES * HEADS;
    float* AD1 = fp; fp += (size_t)N_NODES * HEADS;
    float* AS2 = fp; fp += N_NODES;
    float* AD2 = fp; fp += N_NODES;
    unsigned short* Bp1 = (unsigned short*)fp; fp += 32768;     // 128KB
    unsigned short* Bp2 = (unsigned short*)fp; fp += 32768;     // 128KB
    int* cnt  = (int*)fp;
    int* row  = cnt + N_NODES;            // N+1
    int* pos  = row + N_NODES + 1;        // N
    int* bsum = pos + N_NODES;            // NSCAN
    int* boff = bsum + NSCAN;             // NSCAN
    int* adjS = boff + NSCAN;             // EP
    // layer-2 aliases (written only after their layer-1 uses complete)
    unsigned short* H2b = H1b;                                  // N*128 bf16
    float* XL2 = XL1;                                           // N*128 f32

    int nE = (EP + 255) / 256;

    // ---- CSR build (shared topology) ----
    hipMemsetAsync(cnt, 0, N_NODES * 4, stream);
    hist_kernel<<<nE, 256, 0, stream>>>(ei, cnt);
    scan1_kernel<<<NSCAN, 256, 0, stream>>>(cnt, row, bsum);
    scan2_kernel<<<1, 256, 0, stream>>>(bsum, boff, row + N_NODES);
    scan3_kernel<<<NSCAN, 256, 0, stream>>>(row, boff, pos);
    scatter_kernel<<<nE, 256, 0, stream>>>(ei, pos, adjS);

    // ---- precompute bf16 operands ----
    convx_kernel<<<(N_NODES * (IN_CH / 4) + 255) / 256, 256, 0, stream>>>(x, xb);
    pack1_kernel<<<(128 * 64 + 255) / 256, 256, 0, stream>>>(W1, l1w, Bp1);
    pack2_kernel<<<(128 * 64 + 255) / 256, 256, 0, stream>>>(W2, l2w, Bp2);

    // ---- layer 1 ----
    gemm1_mfma<<<MTILES, 256, 0, stream>>>(xb, Bp1, H1b, XL1);
    att1_kernel<<<(N_NODES + 3) / 4, 256, 0, stream>>>(H1b, as1, ad1, AS1, AD1);
    gather1_kernel<<<N_NODES, 128, 0, stream>>>(row, adjS, AS1, AD1, H1b, XL1,
                                                b1, l1b, HBb);

    // ---- layer 2 ----
    gemm2_mfma<<<MTILES, 256, 0, stream>>>(HBb, Bp2, H2b, XL2);
    att2_kernel<<<(N_NODES + 3) / 4, 256, 0, stream>>>(H2b, as2, ad2, AS2, AD2);
    gather2_kernel<<<N_NODES, 64, 0, stream>>>(row, adjS, AS2, AD2, H2b, XL2,
                                               b2, l2b, out);
}